// Round 18
// baseline (85.463 us; speedup 1.0000x reference)
//
#include <hip/hip_runtime.h>
#include <hip/hip_bf16.h>
#include <stdint.h>

// Problem constants
#define KD 2304    // K = C*3*3
#define LD 3136    // L = 56*56
#define ND 256     // output channels
#define MD 25088   // B*L
#define CD 256     // input channels

typedef __bf16 bf16x8 __attribute__((ext_vector_type(8)));
typedef float f32x4 __attribute__((ext_vector_type(4)));
typedef float f32x4u __attribute__((ext_vector_type(4), aligned(4)));

__device__ __forceinline__ void gload_lds16(const void* g, void* l) {
  __builtin_amdgcn_global_load_lds(
      (const __attribute__((address_space(1))) unsigned int*)g,
      (__attribute__((address_space(3))) unsigned int*)l, 16, 0, 0);
}

// ---------------- Prep: weight fake-quant -> wqT [N][K] bf16 ----------------
__global__ __launch_bounds__(256) void quant_w_kernel(
    const float* __restrict__ w, __hip_bfloat16* __restrict__ wqT) {
  const int gk = blockIdx.x % 72;
  const int gn = blockIdx.x / 72;
  const int n = gn * 32 + (threadIdx.x >> 3);
  const int k = gk * 32 + (threadIdx.x & 7) * 4;
  const float4 v = *(const float4*)(w + (size_t)n * KD + k);
  float a = fmaxf(fmaxf(fabsf(v.x), fabsf(v.y)), fmaxf(fabsf(v.z), fabsf(v.w)));
#pragma unroll
  for (int m = 1; m <= 32; m <<= 1) a = fmaxf(a, __shfl_xor(a, m, 64));
  __shared__ float red[4];
  if ((threadIdx.x & 63) == 0) red[threadIdx.x >> 6] = a;
  __syncthreads();
  const float mx = fmaxf(fmaxf(red[0], red[1]), fmaxf(red[2], red[3]));
  const float r63 = (mx == 0.f) ? 0.f : 63.f / mx;
  const float scale = mx * (1.f / 63.f);
  ushort4 o;
  o.x = __builtin_bit_cast(unsigned short, __float2bfloat16(rintf(v.x * r63) * scale));
  o.y = __builtin_bit_cast(unsigned short, __float2bfloat16(rintf(v.y * r63) * scale));
  o.z = __builtin_bit_cast(unsigned short, __float2bfloat16(rintf(v.z * r63) * scale));
  o.w = __builtin_bit_cast(unsigned short, __float2bfloat16(rintf(v.w * r63) * scale));
  *(ushort4*)((unsigned short*)wqT + (size_t)n * KD + k) = o;
}

// ---- UNIFORM window prefetch DIRECT FROM x: 5 ch x 3 rows = 15 loads ----
// off[di] = l + (di-1)*56 - 1, linear in lane -> coalesced. Clamp to
// [0, CD*LD-4] and REALIGN by d = ad - cl (v[k] <- v[k+d]):
//   d=-1 (c==0 underflow): e0 masked; e1,e2 realigned.
//   d=1,2 (c==255 tail):   d=2 implies j==55 -> e2 masked; rest realigned.
//   |d|>2 only occurs for fully-masked rows (garbage harmless).
__device__ __forceinline__ void qload_x(const float* __restrict__ xb,
                                        const int (&off)[3], int c0,
                                        f32x4u (&win)[5][3]) {
#pragma unroll
  for (int dc = 0; dc < 5; ++dc) {
    const int cdc = (c0 + dc > 255) ? 255 : c0 + dc;   // clamp for tail dummies
    const int cb = cdc * LD;
#pragma unroll
    for (int di = 0; di < 3; ++di) {
      const int ad = cb + off[di];
      int cl = (ad < 0) ? 0 : ad;
      cl = (cl > CD * LD - 4) ? (CD * LD - 4) : cl;
      const int d = ad - cl;
      f32x4u v = *(const f32x4u*)(xb + cl);
      if (d < 0)       { v[2] = v[1]; v[1] = v[0]; }
      else if (d == 1) { v[0] = v[1]; v[1] = v[2]; v[2] = v[3]; }
      else if (d >= 2) { v[0] = v[2]; v[1] = v[3]; }
      win[dc][di] = v;
    }
  }
}

// ---- finish quant -> swizzled As half-tile write (128B rows, 8x16B units) ----
// unit u of row r holds logical unit u^(r&7); row = lane. Boundary masks are
// static-indexed per tap (msk[di][dj], 0.0/1.0 floats).
template <int KP0>
__device__ __forceinline__ void qfinishT(const f32x4u (&win)[5][3],
                                         const float (&msk)[3][3],
                                         char* __restrict__ as_base,
                                         int lane, unsigned cbase) {
  float v[32];
#pragma unroll
  for (int t = 0; t < 32; ++t) {
    const int idx = KP0 + t;
    v[t] = win[idx / 9][(idx % 9) / 3][(idx % 9) % 3] *
           msk[(idx % 9) / 3][(idx % 9) % 3];
  }
  float m16[16];
#pragma unroll
  for (int t = 0; t < 16; ++t)
    m16[t] = fmaxf(__builtin_fabsf(v[2 * t]), __builtin_fabsf(v[2 * t + 1]));
#pragma unroll
  for (int t = 0; t < 8; ++t) m16[t] = fmaxf(m16[t], m16[t + 8]);
#pragma unroll
  for (int t = 0; t < 4; ++t) m16[t] = fmaxf(m16[t], m16[t + 4]);
  const float mx = fmaxf(fmaxf(m16[0], m16[1]), fmaxf(m16[2], m16[3]));
  float r63 = 63.f * __builtin_amdgcn_rcpf(mx);
  r63 = (mx == 0.f) ? 0.f : r63;
  const float scale = mx * (1.f / 63.f);
  unsigned pk[16];
#pragma unroll
  for (int t = 0; t < 16; ++t) {
    const float a = rintf(v[2 * t] * r63) * scale;
    const float b = rintf(v[2 * t + 1] * r63) * scale;
    unsigned d;
    asm("v_cvt_pk_bf16_f32 %0, %1, %2" : "=v"(d) : "v"(a), "v"(b));
    pk[t] = d;
  }
  char* row = as_base + lane * 128;
  const unsigned swz = (unsigned)((lane & 7) << 4);
#pragma unroll
  for (int s = 0; s < 4; ++s) {
    uint4 o = {pk[4 * s], pk[4 * s + 1], pk[4 * s + 2], pk[4 * s + 3]};
    *(uint4*)(row + ((cbase + (unsigned)(s * 16)) ^ swz)) = o;
  }
}

#define SW_FIN(PH, DST, CB)                                                   \
  switch (PH) {                                                               \
    case 0: qfinishT<0>(win, msk, DST, lane, CB); break;                      \
    case 1: qfinishT<1>(win, msk, DST, lane, CB); break;                      \
    case 2: qfinishT<2>(win, msk, DST, lane, CB); break;                      \
    case 3: qfinishT<3>(win, msk, DST, lane, CB); break;                      \
    case 4: qfinishT<4>(win, msk, DST, lane, CB); break;                      \
    case 5: qfinishT<5>(win, msk, DST, lane, CB); break;                      \
    case 6: qfinishT<6>(win, msk, DST, lane, CB); break;                      \
    case 7: qfinishT<7>(win, msk, DST, lane, CB); break;                      \
    default: qfinishT<8>(win, msk, DST, lane, CB); break;                     \
  }

// ---- stage one 256n x 64k wqT half-tile (32KB, 128B rows) — 8 chunks/wave ----
__device__ __forceinline__ void stage_ns(const unsigned short* __restrict__ wsrc,
                                         int k0, int lane, int w,
                                         char* __restrict__ NsH) {
#pragma unroll
  for (int sg = 0; sg < 8; ++sg) {
    const int c = w * 8 + sg;              // 0..31, 1KB chunk = 8 rows x 128B
    const int row = c * 8 + (lane >> 3);   // 0..255
    const int u = (lane & 7) ^ (row & 7);
    gload_lds16(wsrc + (size_t)row * KD + k0 + u * 8, NsH + c * 1024 + lane * 16);
  }
}

// ---- MFMA: 4 waves, wave tile 64n x 64m, BK=128 over 2 half-tiles ----
__device__ __forceinline__ void mfma_phase(
    const char* __restrict__ As0, const char* __restrict__ As1,
    const char* __restrict__ Ns0, const char* __restrict__ Ns1,
    f32x4 (&acc)[4][4], int w, int lq, int hv) {
#pragma unroll
  for (int kk = 0; kk < 4; ++kk) {
    const char* NsH = (kk < 2) ? Ns0 : Ns1;
    const char* AsH = (kk < 2) ? As0 : As1;
    const int kl = kk & 1;
    bf16x8 af[4], bf[4];
#pragma unroll
    for (int i = 0; i < 4; ++i) {
      const unsigned rn = (unsigned)(w * 64 + i * 16 + lq);
      const unsigned u = (unsigned)((kl * 4 + hv) ^ (rn & 7));
      af[i] = *(const bf16x8*)(NsH + rn * 128u + u * 16u);
    }
#pragma unroll
    for (int j = 0; j < 4; ++j) {
      const unsigned rm = (unsigned)(j * 16 + lq);
      const unsigned u = (unsigned)((kl * 4 + hv) ^ (rm & 7));
      bf[j] = *(const bf16x8*)(AsH + rm * 128u + u * 16u);
    }
#pragma unroll
    for (int i = 0; i < 4; ++i)
#pragma unroll
      for (int j = 0; j < 4; ++j)
        acc[i][j] = __builtin_amdgcn_mfma_f32_16x16x32_bf16(
            af[i], bf[j], acc[i][j], 0, 0, 0);
  }
}

// ---------------- Fused: R14 structure, x read directly (no xpad) ----------------
// BM=64, BN=256 (quant-once), BK=128, 4 waves, 18 steps, grid 392 XCD-swizzled.
// LDS 80KB (2 blocks/CU): As 2x8K halves + Ns 2x32K halves, u^(r&7) swizzle.
// Step: stage both Ns halves -> qfinish(win)->As -> qload(R+1) (15 loads cross
// bar) -> bar1{vmcnt(15),lgkm0} -> MFMA (setprio) -> bar2{lgkm0}.
__global__ __launch_bounds__(256, 2) void fused_gemm_kernel(
    const float* __restrict__ x, const __hip_bfloat16* __restrict__ wqT,
    const float* __restrict__ bias, float* __restrict__ out) {
  extern __shared__ char smem[];
  char* As0 = smem;                  // 8KB  (k 0..63 of step)
  char* As1 = smem + 8192;           // 8KB  (k 64..127)
  char* Ns0 = smem + 16384;          // 32KB
  char* Ns1 = smem + 49152;          // 32KB
  const int tid = threadIdx.x;
  const int lane = tid & 63;
  const int w = __builtin_amdgcn_readfirstlane(tid >> 6);   // 0..3

  const int bid = blockIdx.x;                    // 0..391
  const int mt = (bid & 7) * 49 + (bid >> 3);    // XCD swizzle: image d -> XCD d
  const int m0 = mt * 64;

  const int b = m0 / LD;                         // uniform (3136 % 64 == 0)
  const int l = m0 - b * LD + lane;
  const int i = l / 56;
  const int j = l - i * 56;
  const float* xb = x + (size_t)b * CD * LD;
  // per-tap-row address offsets (linear in lane): off[di] = l + (di-1)*56 - 1
  const int off[3] = {l - 57, l - 1, l + 55};
  // boundary masks (0/1 floats), static-indexed per tap in qfinishT
  const float rv0 = (i > 0) ? 1.f : 0.f, rv2 = (i < 55) ? 1.f : 0.f;
  const float cv0 = (j > 0) ? 1.f : 0.f, cv2 = (j < 55) ? 1.f : 0.f;
  const float msk[3][3] = {{rv0 * cv0, rv0, rv0 * cv2},
                           {cv0, 1.f, cv2},
                           {rv2 * cv0, rv2, rv2 * cv2}};
  const unsigned short* wsrc = (const unsigned short*)wqT;

  char* as_dst = (w < 2) ? As0 : As1;            // granule sigma = w
  const unsigned cb = (unsigned)((w & 1) * 64);
  const int lq = lane & 15, hv = lane >> 4;

  f32x4 acc[4][4] = {};
  f32x4u win[5][3];

  // prologue: win for step-0 granule (k = 32w)
  int kq = 32 * w;
  int ph = kq % 9;                               // 0,5,1,6
  qload_x(xb, off, kq / 9, win);

  for (int R = 0; R < 18; ++R) {
    stage_ns(wsrc, R * 128, lane, w, Ns0);       // 8 async gload_lds
    stage_ns(wsrc, R * 128 + 64, lane, w, Ns1);  // 8 async gload_lds
    __builtin_amdgcn_sched_barrier(0);           // pin: stage before win-qload

    SW_FIN(ph, as_dst, cb);                      // consume win -> As half

    kq += 128;
    ph += 2; if (ph >= 9) ph -= 9;
    qload_x(xb, off, kq / 9, win);               // 15 loads cross bar1 (clamped tail)

    // drain the 16 stage loads (older), keep the 15 win loads in flight
    asm volatile("s_waitcnt vmcnt(15) lgkmcnt(0)\n\ts_barrier" ::: "memory");
    __builtin_amdgcn_sched_barrier(0);

    __builtin_amdgcn_s_setprio(1);
    mfma_phase(As0, As1, Ns0, Ns1, acc, w, lq, hv);
    __builtin_amdgcn_s_setprio(0);

    asm volatile("s_waitcnt lgkmcnt(0)\n\ts_barrier" ::: "memory");
    __builtin_amdgcn_sched_barrier(0);
  }

  // ---- Epilogue: D row = n = w*64 + i4*16 + hv*4 + comp, col = m (coalesced) ----
#pragma unroll
  for (int i4 = 0; i4 < 4; ++i4) {
    const int nb = w * 64 + i4 * 16 + hv * 4;
    const float4 b4 = *(const float4*)&bias[nb];
#pragma unroll
    for (int j4 = 0; j4 < 4; ++j4) {
      const int m = m0 + j4 * 16 + lq;
      const int ll = m - b * LD;
      float* op = out + ((size_t)b * ND + nb) * LD + ll;
      op[0]      = acc[i4][j4].x + b4.x;
      op[LD]     = acc[i4][j4].y + b4.y;
      op[2 * LD] = acc[i4][j4].z + b4.z;
      op[3 * LD] = acc[i4][j4].w + b4.w;
    }
  }
}

extern "C" void kernel_launch(void* const* d_in, const int* in_sizes, int n_in,
                              void* d_out, int out_size, void* d_ws, size_t ws_size,
                              hipStream_t stream) {
  const float* x = (const float*)d_in[0];
  const float* wgt = (const float*)d_in[1];
  const float* bias = (const float*)d_in[2];
  float* out = (float*)d_out;

  __hip_bfloat16* wqT = (__hip_bfloat16*)d_ws;   // 256*2304*2 = 1,179,648 B

  quant_w_kernel<<<576, 256, 0, stream>>>(wgt, wqT);
  fused_gemm_kernel<<<392, 256, 80 * 1024, stream>>>(x, wqT, bias, out);
}